// Round 1
// baseline (63.651 us; speedup 1.0000x reference)
//
#include <hip/hip_runtime.h>
#include <math.h>

#define BATCH 16
#define NKER  16
#define KS    5
#define UNITS 10
#define HIN   28
#define HOUT  24       // 28-5+1
#define PO    12       // pooled 12x12
#define NPOOL (PO*PO)  // 144
#define NTASK (NKER*NPOOL) // 2304
#define NC    (KS*KS)  // 25 patch channels

__global__ __launch_bounds__(256) void vdp_forward(
    const float* __restrict__ x,       // [B,1,28,28]
    const float* __restrict__ conv_w,  // [K,1,5,5]
    const float* __restrict__ conv_s,  // [K]
    const float* __restrict__ fc_w,    // [2304,10]
    const float* __restrict__ fc_s,    // [10]
    float* __restrict__ out)           // [B*10] p ++ [B*100] sigma_out
{
    const int b = blockIdx.x;
    const int t = threadIdx.x;

    __shared__ float xs[HIN*HIN];       // 784
    __shared__ float cw[NKER*NC];       // 400
    __shared__ float sp1[NKER];
    __shared__ float sp2[UNITS];
    __shared__ float mu3_s[NTASK];      // 2304
    __shared__ short idx_s[NTASK];      // 2304
    __shared__ float T_s[NKER][UNITS][NC]; // 4000
    __shared__ float red_s[4][12];
    __shared__ float fin_s[12];         // [tr, mnorm, mu4[10]]
    __shared__ float s4_s[UNITS*UNITS];
    __shared__ float tmp_s[UNITS*UNITS];
    __shared__ float p_s[UNITS];
    __shared__ float r_s[UNITS];
    __shared__ float q_s[UNITS];

    // ---- stage inputs ----
    for (int i = t; i < HIN*HIN; i += 256) xs[i] = x[b*HIN*HIN + i];
    for (int i = t; i < NKER*NC; i += 256) cw[i] = conv_w[i];
    if (t < NKER)  sp1[t] = log1pf(expf(conv_s[t]));
    if (t < UNITS) sp2[t] = log1pf(expf(fc_s[t]));
    __syncthreads();

    // ---- phase 1: conv + relu + maxpool (fused). per task = (k, pooled cell) ----
    float pt_tr = 0.f, pt_mn = 0.f;
    float pmu4[UNITS];
    #pragma unroll
    for (int u = 0; u < UNITS; ++u) pmu4[u] = 0.f;

    for (int task = t; task < NTASK; task += 256) {
        const int k  = task / NPOOL;
        const int m  = task - k*NPOOL;
        const int pi = m / PO, pj = m - pi*PO;
        float bestv = -1.f;
        int   besta = 0;
        #pragma unroll
        for (int a = 0; a < 4; ++a) {          // window order (dh,dw): (0,0),(0,1),(1,0),(1,1)
            const int oh = 2*pi + (a >> 1);
            const int ow = 2*pj + (a & 1);
            float acc = 0.f;
            #pragma unroll
            for (int kh = 0; kh < KS; ++kh)
                #pragma unroll
                for (int kw = 0; kw < KS; ++kw)
                    acc = fmaf(cw[k*NC + kh*KS + kw], xs[(oh+kh)*HIN + ow + kw], acc);
            const float rv = fmaxf(acc, 0.f);
            if (rv > bestv) { bestv = rv; besta = a; }  // first-max wins (jnp.argmax)
        }
        const int oh = 2*pi + (besta >> 1);
        const int ow = 2*pj + (besta & 1);
        const float mu3 = bestv;               // = relu(max mu1); g_tilde = (mu3 > 0)
        mu3_s[task] = mu3;
        idx_s[task] = (short)(oh*HOUT + ow);
        if (mu3 > 0.f) {                       // trace term: sp1[k] * ||patch||^2
            float ns = 0.f;
            #pragma unroll
            for (int kh = 0; kh < KS; ++kh)
                #pragma unroll
                for (int kw = 0; kw < KS; ++kw) {
                    const float v = xs[(oh+kh)*HIN + ow + kw];
                    ns = fmaf(v, v, ns);
                }
            pt_tr += sp1[k]*ns;
        }
        pt_mn = fmaf(mu3, mu3, pt_mn);
        const float* fr = fc_w + task*UNITS;   // row (k*144 + m) of fc_w_mu
        #pragma unroll
        for (int u = 0; u < UNITS; ++u) pmu4[u] = fmaf(mu3, fr[u], pmu4[u]);
    }

    // ---- reduce [tr, mnorm, mu4[10]] across 256 threads (deterministic tree) ----
    {
        float vals[12];
        vals[0] = pt_tr; vals[1] = pt_mn;
        #pragma unroll
        for (int u = 0; u < UNITS; ++u) vals[2+u] = pmu4[u];
        #pragma unroll
        for (int off = 32; off >= 1; off >>= 1)
            #pragma unroll
            for (int j = 0; j < 12; ++j)
                vals[j] += __shfl_down(vals[j], off);
        const int wid = t >> 6, lane = t & 63;
        if (lane == 0)
            #pragma unroll
            for (int j = 0; j < 12; ++j) red_s[wid][j] = vals[j];
    }
    __syncthreads();
    if (t < 12) fin_s[t] = red_s[0][t] + red_s[1][t] + red_s[2][t] + red_s[3][t];
    __syncthreads();

    // ---- phase 2: T[k,u,c] = sum_i fcw[k,i,u]*g_i*xm[idx_i, c]. task = (k,c), 400 tasks ----
    for (int kc = t; kc < NKER*NC; kc += 256) {
        const int k  = kc / NC, c = kc - k*NC;
        const int kh = c / KS, kw = c - kh*KS;
        float acc[UNITS];
        #pragma unroll
        for (int u = 0; u < UNITS; ++u) acc[u] = 0.f;
        const int base = k*NPOOL;
        for (int i = 0; i < NPOOL; ++i) {
            const float mu3 = mu3_s[base + i];
            if (mu3 > 0.f) {
                const int p  = idx_s[base + i];
                const int oh = p / HOUT, ow = p - oh*HOUT;
                const float xv = xs[(oh+kh)*HIN + ow + kw];
                const float* fr = fc_w + (base + i)*UNITS;
                #pragma unroll
                for (int u = 0; u < UNITS; ++u) acc[u] = fmaf(fr[u], xv, acc[u]);
            }
        }
        #pragma unroll
        for (int u = 0; u < UNITS; ++u) T_s[k][u][c] = acc[u];
    }
    __syncthreads();

    // ---- phase 3: sigma4 = sigma_a + diag(sp2*(tr+mnorm)); softmax on mu4 ----
    if (t < UNITS*UNITS) {
        const int u = t / UNITS, v = t - u*UNITS;
        float acc = 0.f;
        for (int k = 0; k < NKER; ++k) {
            float s = 0.f;
            #pragma unroll
            for (int c = 0; c < NC; ++c) s = fmaf(T_s[k][u][c], T_s[k][v][c], s);
            acc = fmaf(sp1[k], s, acc);
        }
        if (u == v) acc += sp2[u]*(fin_s[0] + fin_s[1]);
        s4_s[t] = acc;
    }
    if (t == 255) {  // softmax(mu4) in parallel with sigma4 (disjoint threads/memory)
        float mx = fin_s[2];
        #pragma unroll
        for (int u = 1; u < UNITS; ++u) mx = fmaxf(mx, fin_s[2+u]);
        float s = 0.f;
        float e[UNITS];
        #pragma unroll
        for (int u = 0; u < UNITS; ++u) { e[u] = expf(fin_s[2+u] - mx); s += e[u]; }
        #pragma unroll
        for (int u = 0; u < UNITS; ++u) p_s[u] = e[u] / s;
    }
    __syncthreads();

    // ---- phase 4: sigma_out = grad @ sigma4 @ grad^T, grad = diag(p) - p p^T ----
    // tmp[i,k] = p_i*(s4[i,k] - r[k]),  r[k] = sum_j p_j*s4[j,k]
    if (t < UNITS) {
        float r = 0.f;
        #pragma unroll
        for (int j = 0; j < UNITS; ++j) r = fmaf(p_s[j], s4_s[j*UNITS + t], r);
        r_s[t] = r;
    }
    __syncthreads();
    if (t < UNITS*UNITS) {
        const int i = t / UNITS, k2 = t - i*UNITS;
        tmp_s[t] = p_s[i]*(s4_s[t] - r_s[k2]);
    }
    __syncthreads();
    // q[i] = sum_k tmp[i,k]*p_k ; sigma_out[i,l] = p_l*(tmp[i,l] - q[i])
    if (t < UNITS) {
        float q = 0.f;
        #pragma unroll
        for (int k = 0; k < UNITS; ++k) q = fmaf(tmp_s[t*UNITS + k], p_s[k], q);
        q_s[t] = q;
    }
    __syncthreads();
    if (t < UNITS*UNITS) {
        const int i = t / UNITS, l = t - i*UNITS;
        out[BATCH*UNITS + b*UNITS*UNITS + t] = p_s[l]*(tmp_s[i*UNITS + l] - q_s[i]);
    }
    if (t < UNITS) out[b*UNITS + t] = p_s[t];
}

extern "C" void kernel_launch(void* const* d_in, const int* in_sizes, int n_in,
                              void* d_out, int out_size, void* d_ws, size_t ws_size,
                              hipStream_t stream) {
    const float* x      = (const float*)d_in[0];
    const float* conv_w = (const float*)d_in[1];
    const float* conv_s = (const float*)d_in[2];
    const float* fc_w   = (const float*)d_in[3];
    const float* fc_s   = (const float*)d_in[4];
    float* out = (float*)d_out;
    vdp_forward<<<BATCH, 256, 0, stream>>>(x, conv_w, conv_s, fc_w, fc_s, out);
}

// Round 2
// 32.263 us; speedup vs baseline: 1.9729x; 1.9729x over previous
//
#include <hip/hip_runtime.h>
#include <math.h>

#define BATCH 16
#define NKER  16
#define KS    5
#define UNITS 10
#define HIN   28
#define HOUT  24       // 28-5+1
#define PO    12       // pooled 12x12
#define NPOOL (PO*PO)  // 144
#define NC    (KS*KS)  // 25 patch channels
#define PART  112      // per-(b,k) partial: A[100] + mu4[10] + tr + mn

// ---------------- Stage 1: one block per (b,k) ----------------
__global__ __launch_bounds__(256) void vdp_stage1(
    const float* __restrict__ x,       // [B,1,28,28]
    const float* __restrict__ conv_w,  // [K,1,5,5]
    const float* __restrict__ conv_s,  // [K]
    const float* __restrict__ fc_w,    // [2304,10]
    float* __restrict__ ws)            // [B*K][PART]
{
    const int bk = blockIdx.x;
    const int b  = bk >> 4;
    const int k  = bk & 15;
    const int t  = threadIdx.x;

    __shared__ float xs[HIN*HIN];          // 784
    __shared__ float cw[NC];               // 25 (this k only)
    __shared__ float fcw_s[NPOOL*UNITS];   // 1440 (rows k*144..k*144+143)
    __shared__ float mu3_s[NPOOL];
    __shared__ int   idx_s[NPOOL];
    __shared__ float T_s[UNITS*NC];        // 250, layout [u][c]
    __shared__ float red_s[4][12];
    __shared__ float fin_s[12];            // [tr_raw, mn, mu4[10]]
    __shared__ float sp1s;

    // stage inputs
    for (int i = t; i < HIN*HIN; i += 256) xs[i] = x[b*HIN*HIN + i];
    if (t < NC) cw[t] = conv_w[k*NC + t];
    for (int i = t; i < NPOOL*UNITS; i += 256) fcw_s[i] = fc_w[k*NPOOL*UNITS + i];
    if (t == 0) sp1s = log1pf(expf(conv_s[k]));
    __syncthreads();

    // phase 1: conv + relu + maxpool, one pooled cell per thread
    float v_tr = 0.f, v_mn = 0.f;
    float v_mu[UNITS];
    #pragma unroll
    for (int u = 0; u < UNITS; ++u) v_mu[u] = 0.f;

    if (t < NPOOL) {
        const int pi = t / PO, pj = t - pi*PO;
        float bestv = -1.f;
        int   besta = 0;
        #pragma unroll
        for (int a = 0; a < 4; ++a) {        // window order (0,0),(0,1),(1,0),(1,1)
            const int oh = 2*pi + (a >> 1);
            const int ow = 2*pj + (a & 1);
            float acc = 0.f;
            #pragma unroll
            for (int kh = 0; kh < KS; ++kh)
                #pragma unroll
                for (int kw = 0; kw < KS; ++kw)
                    acc = fmaf(cw[kh*KS + kw], xs[(oh+kh)*HIN + ow + kw], acc);
            const float rv = fmaxf(acc, 0.f);
            if (rv > bestv) { bestv = rv; besta = a; }   // first-max wins (jnp.argmax)
        }
        const int oh = 2*pi + (besta >> 1);
        const int ow = 2*pj + (besta & 1);
        const float mu3 = bestv;
        mu3_s[t] = mu3;
        idx_s[t] = oh*HOUT + ow;
        if (mu3 > 0.f) {                      // g_i = 1: trace term ||patch||^2
            float ns = 0.f;
            #pragma unroll
            for (int kh = 0; kh < KS; ++kh)
                #pragma unroll
                for (int kw = 0; kw < KS; ++kw) {
                    const float v = xs[(oh+kh)*HIN + ow + kw];
                    ns = fmaf(v, v, ns);
                }
            v_tr = ns;
        }
        v_mn = mu3*mu3;
        #pragma unroll
        for (int u = 0; u < UNITS; ++u) v_mu[u] = mu3*fcw_s[t*UNITS + u];
    }

    // deterministic tree-reduce 12 values over the block (t>=144 contribute 0)
    {
        float vals[12];
        vals[0] = v_tr; vals[1] = v_mn;
        #pragma unroll
        for (int u = 0; u < UNITS; ++u) vals[2+u] = v_mu[u];
        #pragma unroll
        for (int off = 32; off >= 1; off >>= 1)
            #pragma unroll
            for (int j = 0; j < 12; ++j)
                vals[j] += __shfl_down(vals[j], off);
        const int wid = t >> 6, lane = t & 63;
        if (lane == 0)
            #pragma unroll
            for (int j = 0; j < 12; ++j) red_s[wid][j] = vals[j];
    }
    __syncthreads();

    // phase 2: T[u,c] = sum_i fcw[i,u]*g_i*xm[idx_i,c]; 250 threads, 144-iter loop
    if (t < 12) fin_s[t] = red_s[0][t] + red_s[1][t] + red_s[2][t] + red_s[3][t];
    if (t < UNITS*NC) {
        const int c = t / UNITS, u = t - c*UNITS;
        const int kh = c / KS, kw = c - kh*KS;
        float acc = 0.f;
        for (int i = 0; i < NPOOL; ++i) {
            const float mu3 = mu3_s[i];
            if (mu3 > 0.f) {                 // uniform branch (same i for all threads)
                const int p  = idx_s[i];
                const int oh = p / HOUT, ow = p - oh*HOUT;
                acc = fmaf(fcw_s[i*UNITS + u], xs[(oh+kh)*HIN + ow + kw], acc);
            }
        }
        T_s[u*NC + c] = acc;
    }
    __syncthreads();

    // phase 3: A[u,v] = sp1 * sum_c T[u,c]*T[v,c]; write partials
    float* wsp = ws + bk*PART;
    if (t < UNITS*UNITS) {
        const int u = t / UNITS, v = t - u*UNITS;
        float s = 0.f;
        #pragma unroll
        for (int c = 0; c < NC; ++c) s = fmaf(T_s[u*NC + c], T_s[v*NC + c], s);
        wsp[t] = sp1s * s;
    } else if (t < UNITS*UNITS + UNITS) {
        wsp[t] = fin_s[2 + (t - UNITS*UNITS)];       // mu4 partial
    } else if (t == PART - 2) {
        wsp[PART-2] = sp1s * fin_s[0];               // tr partial (sp1 applied)
    } else if (t == PART - 1) {
        wsp[PART-1] = fin_s[1];                      // mnorm partial
    }
}

// ---------------- Stage 2: one block per b ----------------
__global__ __launch_bounds__(128) void vdp_stage2(
    const float* __restrict__ ws,      // [B*K][PART]
    const float* __restrict__ fc_s,    // [10]
    float* __restrict__ out)           // [B*10] p ++ [B*100] sigma_out
{
    const int b = blockIdx.x;
    const int t = threadIdx.x;

    __shared__ float s[PART];
    __shared__ float s4[UNITS*UNITS];
    __shared__ float tmp[UNITS*UNITS];
    __shared__ float p_s[UNITS];
    __shared__ float r_s[UNITS];
    __shared__ float q_s[UNITS];
    __shared__ float sp2[UNITS];

    if (t < PART) {
        float a = 0.f;
        #pragma unroll
        for (int k = 0; k < NKER; ++k) a += ws[(b*NKER + k)*PART + t];
        s[t] = a;
    }
    if (t < UNITS) sp2[t] = log1pf(expf(fc_s[t]));
    __syncthreads();

    if (t < UNITS*UNITS) {
        const int u = t / UNITS, v = t - u*UNITS;
        float a = s[t];
        if (u == v) a += sp2[u]*(s[PART-2] + s[PART-1]);
        s4[t] = a;
    }
    if (t == 112) {   // softmax(mu4), idle lane of wave 1
        float mx = s[100];
        #pragma unroll
        for (int u = 1; u < UNITS; ++u) mx = fmaxf(mx, s[100+u]);
        float sum = 0.f;
        float e[UNITS];
        #pragma unroll
        for (int u = 0; u < UNITS; ++u) { e[u] = expf(s[100+u] - mx); sum += e[u]; }
        #pragma unroll
        for (int u = 0; u < UNITS; ++u) p_s[u] = e[u] / sum;
    }
    __syncthreads();

    // sigma_out = G s4 G^T with G = diag(p) - p p^T
    if (t < UNITS) {
        float r = 0.f;
        #pragma unroll
        for (int j = 0; j < UNITS; ++j) r = fmaf(p_s[j], s4[j*UNITS + t], r);
        r_s[t] = r;
    }
    __syncthreads();
    if (t < UNITS*UNITS) {
        const int i = t / UNITS, k2 = t - i*UNITS;
        tmp[t] = p_s[i]*(s4[t] - r_s[k2]);
    }
    __syncthreads();
    if (t < UNITS) {
        float q = 0.f;
        #pragma unroll
        for (int k = 0; k < UNITS; ++k) q = fmaf(tmp[t*UNITS + k], p_s[k], q);
        q_s[t] = q;
    }
    __syncthreads();
    if (t < UNITS*UNITS) {
        const int i = t / UNITS, l = t - i*UNITS;
        out[BATCH*UNITS + b*UNITS*UNITS + t] = p_s[l]*(tmp[i*UNITS + l] - q_s[i]);
    }
    if (t < UNITS) out[b*UNITS + t] = p_s[t];
}

extern "C" void kernel_launch(void* const* d_in, const int* in_sizes, int n_in,
                              void* d_out, int out_size, void* d_ws, size_t ws_size,
                              hipStream_t stream) {
    const float* x      = (const float*)d_in[0];
    const float* conv_w = (const float*)d_in[1];
    const float* conv_s = (const float*)d_in[2];
    const float* fc_w   = (const float*)d_in[3];
    const float* fc_s   = (const float*)d_in[4];
    float* out = (float*)d_out;
    float* ws  = (float*)d_ws;   // needs BATCH*NKER*PART*4 = 114688 bytes

    vdp_stage1<<<BATCH*NKER, 256, 0, stream>>>(x, conv_w, conv_s, fc_w, ws);
    vdp_stage2<<<BATCH, 128, 0, stream>>>(ws, fc_s, out);
}

// Round 3
// 14.480 us; speedup vs baseline: 4.3958x; 2.2281x over previous
//
#include <hip/hip_runtime.h>
#include <math.h>

#define BATCH 16
#define NKER  16
#define KS    5
#define UNITS 10
#define HIN   28
#define HOUT  24       // 28-5+1
#define PO    12       // pooled 12x12
#define NPOOL (PO*PO)  // 144
#define NC    (KS*KS)  // 25 patch channels
#define PCOLS 26       // padded patch columns (c=25 is zero)
#define PART  112      // per-(b,k) partial: A[100] + mu4[10] + tr + mn

// ---------------- Stage 1: one block per (b,k) ----------------
__global__ __launch_bounds__(256) void vdp_stage1(
    const float* __restrict__ x,       // [B,1,28,28]
    const float* __restrict__ conv_w,  // [K,1,5,5]
    const float* __restrict__ conv_s,  // [K]
    const float* __restrict__ fc_w,    // [2304,10]
    float* __restrict__ ws)            // [B*K][PART]
{
    const int bk = blockIdx.x;
    const int b  = bk >> 4;
    const int k  = bk & 15;
    const int t  = threadIdx.x;

    __shared__ float xs[HIN*HIN];          // 784
    __shared__ float cw[NC];               // 25 (this k only)
    __shared__ float fcw_s[NPOOL*UNITS];   // 1440 (rows k*144..k*144+143)
    __shared__ float P_s[NPOOL*PCOLS];     // 3744: gated argmax patches
    __shared__ float T_s[UNITS*PCOLS];     // 260
    __shared__ float red_s[4][12];
    __shared__ float fin_s[12];            // [tr_raw, mn, mu4[10]]
    __shared__ float sp1s;

    // ---- stage inputs (vectorized; both bases 16B-aligned) ----
    {
        const float4* x4 = reinterpret_cast<const float4*>(x + b*HIN*HIN);
        float4* xs4 = reinterpret_cast<float4*>(xs);
        for (int i = t; i < HIN*HIN/4; i += 256) xs4[i] = x4[i];
        const float4* f4 = reinterpret_cast<const float4*>(fc_w + k*NPOOL*UNITS);
        float4* fs4 = reinterpret_cast<float4*>(fcw_s);
        for (int i = t; i < NPOOL*UNITS/4; i += 256) fs4[i] = f4[i];
        if (t < NC) cw[t] = conv_w[k*NC + t];
        if (t == 0) sp1s = log1pf(expf(conv_s[k]));
    }
    __syncthreads();

    // ---- phase 1: conv + relu + argmax-pool, one pooled cell per thread ----
    float v_tr = 0.f, v_mn = 0.f;
    float v_mu[UNITS];
    #pragma unroll
    for (int u = 0; u < UNITS; ++u) v_mu[u] = 0.f;

    if (t < NPOOL) {
        const int pi = t / PO, pj = t - pi*PO;
        // 6x6 input window into registers (static indices everywhere after)
        float w6[36];
        #pragma unroll
        for (int r = 0; r < 6; ++r)
            #pragma unroll
            for (int cc = 0; cc < 6; ++cc)
                w6[r*6 + cc] = xs[(2*pi + r)*HIN + 2*pj + cc];
        float cwr[NC];
        #pragma unroll
        for (int c = 0; c < NC; ++c) cwr[c] = cw[c];

        float a0 = 0.f, a1 = 0.f, a2 = 0.f, a3 = 0.f;
        #pragma unroll
        for (int kh = 0; kh < KS; ++kh)
            #pragma unroll
            for (int kw = 0; kw < KS; ++kw) {
                const float w = cwr[kh*KS + kw];
                a0 = fmaf(w, w6[kh*6 + kw],       a0);
                a1 = fmaf(w, w6[kh*6 + kw + 1],   a1);
                a2 = fmaf(w, w6[(kh+1)*6 + kw],   a2);
                a3 = fmaf(w, w6[(kh+1)*6 + kw+1], a3);
            }
        const float r0 = fmaxf(a0, 0.f), r1 = fmaxf(a1, 0.f);
        const float r2 = fmaxf(a2, 0.f), r3 = fmaxf(a3, 0.f);
        float bestv = r0; int besta = 0;               // first-max wins (jnp.argmax)
        if (r1 > bestv) { bestv = r1; besta = 1; }
        if (r2 > bestv) { bestv = r2; besta = 2; }
        if (r3 > bestv) { bestv = r3; besta = 3; }
        const float mu3 = bestv;
        const float g   = (mu3 > 0.f) ? 1.f : 0.f;

        // gated patch -> LDS (branch-free select, static reg indices)
        float ns = 0.f;
        #pragma unroll
        for (int kh = 0; kh < KS; ++kh)
            #pragma unroll
            for (int kw = 0; kw < KS; ++kw) {
                const float v0 = w6[kh*6 + kw];
                const float v1 = w6[kh*6 + kw + 1];
                const float v2 = w6[(kh+1)*6 + kw];
                const float v3 = w6[(kh+1)*6 + kw + 1];
                const float val = (besta < 2) ? ((besta == 0) ? v0 : v1)
                                              : ((besta == 2) ? v2 : v3);
                const float pv = g * val;
                P_s[t*PCOLS + kh*KS + kw] = pv;
                ns = fmaf(pv, pv, ns);                 // = g * ||patch||^2 (g in {0,1})
            }
        P_s[t*PCOLS + NC] = 0.f;                       // pad column
        v_tr = ns;
        v_mn = mu3*mu3;
        #pragma unroll
        for (int u = 0; u < UNITS; ++u) v_mu[u] = mu3*fcw_s[t*UNITS + u];
    }

    // ---- deterministic tree-reduce 12 values over the block ----
    {
        float vals[12];
        vals[0] = v_tr; vals[1] = v_mn;
        #pragma unroll
        for (int u = 0; u < UNITS; ++u) vals[2+u] = v_mu[u];
        #pragma unroll
        for (int off = 32; off >= 1; off >>= 1)
            #pragma unroll
            for (int j = 0; j < 12; ++j)
                vals[j] += __shfl_down(vals[j], off);
        const int wid = t >> 6, lane = t & 63;
        if (lane == 0)
            #pragma unroll
            for (int j = 0; j < 12; ++j) red_s[wid][j] = vals[j];
    }
    __syncthreads();
    if (t < 12) fin_s[t] = red_s[0][t] + red_s[1][t] + red_s[2][t] + red_s[3][t];

    // ---- phase 2: T[u,c] = sum_i fcw[i,u]*P[i,c] — dense, branch-free, pipelined ----
    if (t < UNITS*13) {                    // u in [0,10), c-pair j in [0,13)
        const int u = t / 13, j = t - u*13;
        const int c0 = 2*j;
        float acc0 = 0.f, acc1 = 0.f;
        #pragma unroll 8
        for (int i = 0; i < NPOOL; ++i) {
            const float w = fcw_s[i*UNITS + u];
            const float2 pv = *reinterpret_cast<const float2*>(&P_s[i*PCOLS + c0]);
            acc0 = fmaf(w, pv.x, acc0);
            acc1 = fmaf(w, pv.y, acc1);
        }
        T_s[u*PCOLS + c0]     = acc0;
        T_s[u*PCOLS + c0 + 1] = acc1;
    }
    __syncthreads();

    // ---- phase 3: A[u,v] = sp1 * sum_c T[u,c]*T[v,c]; write 112 partials ----
    float* wsp = ws + bk*PART;
    if (t < UNITS*UNITS) {
        const int u = t / UNITS, v = t - u*UNITS;
        float s = 0.f;
        #pragma unroll
        for (int c = 0; c < NC; ++c) s = fmaf(T_s[u*PCOLS + c], T_s[v*PCOLS + c], s);
        wsp[t] = sp1s * s;
    } else if (t < UNITS*UNITS + UNITS) {
        wsp[t] = fin_s[2 + (t - UNITS*UNITS)];       // mu4 partial
    } else if (t == PART - 2) {
        wsp[PART-2] = sp1s * fin_s[0];               // tr partial (sp1 applied)
    } else if (t == PART - 1) {
        wsp[PART-1] = fin_s[1];                      // mnorm partial
    }
}

// ---------------- Stage 2: one block per b ----------------
__global__ __launch_bounds__(128) void vdp_stage2(
    const float* __restrict__ ws,      // [B*K][PART]
    const float* __restrict__ fc_s,    // [10]
    float* __restrict__ out)           // [B*10] p ++ [B*100] sigma_out
{
    const int b = blockIdx.x;
    const int t = threadIdx.x;

    __shared__ float s[PART];
    __shared__ float s4[UNITS*UNITS];
    __shared__ float tmp[UNITS*UNITS];
    __shared__ float p_s[UNITS];
    __shared__ float r_s[UNITS];
    __shared__ float q_s[UNITS];
    __shared__ float sp2[UNITS];

    if (t < PART) {
        float a = 0.f;
        #pragma unroll
        for (int k = 0; k < NKER; ++k) a += ws[(b*NKER + k)*PART + t];
        s[t] = a;
    }
    if (t < UNITS) sp2[t] = log1pf(expf(fc_s[t]));
    __syncthreads();

    if (t < UNITS*UNITS) {
        const int u = t / UNITS, v = t - u*UNITS;
        float a = s[t];
        if (u == v) a += sp2[u]*(s[PART-2] + s[PART-1]);
        s4[t] = a;
    }
    if (t == 112) {   // softmax(mu4), idle lane
        float mx = s[100];
        #pragma unroll
        for (int u = 1; u < UNITS; ++u) mx = fmaxf(mx, s[100+u]);
        float sum = 0.f;
        float e[UNITS];
        #pragma unroll
        for (int u = 0; u < UNITS; ++u) { e[u] = expf(s[100+u] - mx); sum += e[u]; }
        #pragma unroll
        for (int u = 0; u < UNITS; ++u) p_s[u] = e[u] / sum;
    }
    __syncthreads();

    // sigma_out = G s4 G^T with G = diag(p) - p p^T
    if (t < UNITS) {
        float r = 0.f;
        #pragma unroll
        for (int j = 0; j < UNITS; ++j) r = fmaf(p_s[j], s4[j*UNITS + t], r);
        r_s[t] = r;
    }
    __syncthreads();
    if (t < UNITS*UNITS) {
        const int i = t / UNITS, k2 = t - i*UNITS;
        tmp[t] = p_s[i]*(s4[t] - r_s[k2]);
    }
    __syncthreads();
    if (t < UNITS) {
        float q = 0.f;
        #pragma unroll
        for (int k = 0; k < UNITS; ++k) q = fmaf(tmp[t*UNITS + k], p_s[k], q);
        q_s[t] = q;
    }
    __syncthreads();
    if (t < UNITS*UNITS) {
        const int i = t / UNITS, l = t - i*UNITS;
        out[BATCH*UNITS + b*UNITS*UNITS + t] = p_s[l]*(tmp[i*UNITS + l] - q_s[i]);
    }
    if (t < UNITS) out[b*UNITS + t] = p_s[t];
}

extern "C" void kernel_launch(void* const* d_in, const int* in_sizes, int n_in,
                              void* d_out, int out_size, void* d_ws, size_t ws_size,
                              hipStream_t stream) {
    const float* x      = (const float*)d_in[0];
    const float* conv_w = (const float*)d_in[1];
    const float* conv_s = (const float*)d_in[2];
    const float* fc_w   = (const float*)d_in[3];
    const float* fc_s   = (const float*)d_in[4];
    float* out = (float*)d_out;
    float* ws  = (float*)d_ws;   // BATCH*NKER*PART*4 = 114688 bytes

    vdp_stage1<<<BATCH*NKER, 256, 0, stream>>>(x, conv_w, conv_s, fc_w, ws);
    vdp_stage2<<<BATCH, 128, 0, stream>>>(ws, fc_s, out);
}